// Round 3
// baseline (75.630 us; speedup 1.0000x reference)
//
#include <hip/hip_runtime.h>

#define EPS 1e-10f

constexpr int B_ = 64, K_ = 4, M_ = 3, P_ = 65536;
constexpr int THREADS = 256;
constexpr int CHUNK = 2048;                    // pixels per block
constexpr int BLOCKS_PER_B = P_ / CHUNK;       // 32  -> grid = 2048 blocks
constexpr int VPT = CHUNK / 4 / THREADS;       // float4 iterations per thread = 2
constexpr int NACC = 29;                       // 4 s + 12 t + 12 u + 1 n

// ---------------- pass 1: per-(b,k) weighted sums -------------------------
// __launch_bounds__(256,4): 4 blocks/CU -> VGPR budget 128, lets the
// allocator keep a full iteration (36 VGPR of loads) + 29 accumulators live.
__global__ __launch_bounds__(THREADS, 4) void gmm_pass1(
    const float* __restrict__ pred, const float* __restrict__ inp,
    const int* __restrict__ heart, float* __restrict__ sums)
{
    const int blk   = blockIdx.x;
    const int b     = blk / BLOCKS_PER_B;
    const int chunk = blk % BLOCKS_PER_B;
    const int tid   = threadIdx.x;

    const float4* pb = (const float4*)(pred + (size_t)b * K_ * P_);
    const float4* ib = (const float4*)(inp  + (size_t)b * M_ * P_);
    const int4*   hb = (const int4*)(heart + (size_t)b * P_);
    const int vbase = chunk * (CHUNK / 4);

    float sacc[K_];
    float tacc[K_][M_];
    float uacc[K_][M_];
    float nacc = 0.f;
    #pragma unroll
    for (int k = 0; k < K_; ++k) {
        sacc[k] = 0.f;
        #pragma unroll
        for (int m = 0; m < M_; ++m) { tacc[k][m] = 0.f; uacc[k][m] = 0.f; }
    }

    #pragma unroll
    for (int it = 0; it < VPT; ++it) {
        const int v = vbase + it * THREADS + tid;
        const int4 h4 = hb[v];
        float4 pk[K_];
        float4 xm[M_];
        #pragma unroll
        for (int k = 0; k < K_; ++k) pk[k] = pb[k * (P_ / 4) + v];
        #pragma unroll
        for (int m = 0; m < M_; ++m) xm[m] = ib[m * (P_ / 4) + v];

        #define PIX1(C) do {                                                  \
            const float w = (h4.C == 1) ? 1.f : 0.f;                          \
            nacc += w;                                                        \
            _Pragma("unroll")                                                 \
            for (int k = 0; k < K_; ++k) {                                    \
                const float pw = pk[k].C * w;                                 \
                sacc[k] += pw;                                                \
                _Pragma("unroll")                                             \
                for (int m = 0; m < M_; ++m) {                                \
                    const float x = xm[m].C;                                  \
                    tacc[k][m] = fmaf(pw,     x, tacc[k][m]);                 \
                    uacc[k][m] = fmaf(pw * x, x, uacc[k][m]);                 \
                }                                                             \
            }                                                                 \
        } while (0)
        PIX1(x); PIX1(y); PIX1(z); PIX1(w);
        #undef PIX1
    }

    float acc[NACC];
    #pragma unroll
    for (int k = 0; k < K_; ++k) {
        acc[k] = sacc[k];
        #pragma unroll
        for (int m = 0; m < M_; ++m) {
            acc[4  + k * M_ + m] = tacc[k][m];
            acc[16 + k * M_ + m] = uacc[k][m];
        }
    }
    acc[28] = nacc;

    __shared__ float lds[4][NACC];
    const int lane = tid & 63, wid = tid >> 6;
    #pragma unroll
    for (int i = 0; i < NACC; ++i) {
        float v = acc[i];
        #pragma unroll
        for (int off = 32; off; off >>= 1) v += __shfl_down(v, off);
        if (lane == 0) lds[wid][i] = v;
    }
    __syncthreads();
    if (tid < NACC) {
        const float v = lds[0][tid] + lds[1][tid] + lds[2][tid] + lds[3][tid];
        atomicAdd(&sums[b * NACC + tid], v);
    }
}

// ---------------- pass 2: derive mu, 1/(2var), coef, 1/(n*B) --------------
__global__ void gmm_pass2(const float* __restrict__ sums, float* __restrict__ der)
{
    const int t = blockIdx.x * blockDim.x + threadIdx.x;   // = b*K + k
    if (t >= B_ * K_) return;
    const int b = t / K_, k = t % K_;
    const float* sb = sums + b * NACC;
    float* db = der + b * NACC;   // layout: mu[12], iv[12], c[4], invn[1]

    const float s = sb[k] + EPS;
    const float inv_s = 1.f / s;
    float c = 1.f;
    #pragma unroll
    for (int m = 0; m < M_; ++m) {
        const float tkm = sb[4  + k * M_ + m];
        const float ukm = sb[16 + k * M_ + m];
        const float mu  = tkm * inv_s;
        const float var = fmaf(-mu, mu, ukm * inv_s) + EPS;
        db[k * M_ + m]      = mu;
        db[12 + k * M_ + m] = 0.5f / var;
        c *= rsqrtf(6.283185307179586f * var);
    }
    db[24 + k] = c;
    if (k == 0) db[28] = 1.f / (sb[28] * (float)B_);
}

// ---------------- pass 3: mixture log-likelihood, masked mean -------------
__global__ __launch_bounds__(THREADS, 4) void gmm_pass3(
    const float* __restrict__ pred, const float* __restrict__ inp,
    const int* __restrict__ heart, const float* __restrict__ der,
    float* __restrict__ out)
{
    const int blk   = blockIdx.x;
    const int b     = blk / BLOCKS_PER_B;
    const int chunk = blk % BLOCKS_PER_B;
    const int tid   = threadIdx.x;

    const float* db = der + b * NACC;
    float mu[K_][M_], iv[K_][M_], ck[K_];
    #pragma unroll
    for (int k = 0; k < K_; ++k) {
        #pragma unroll
        for (int m = 0; m < M_; ++m) {
            mu[k][m] = db[k * M_ + m];
            iv[k][m] = db[12 + k * M_ + m];
        }
        ck[k] = db[24 + k];
    }
    const float invn = db[28];

    const float4* pb = (const float4*)(pred + (size_t)b * K_ * P_);
    const float4* ib = (const float4*)(inp  + (size_t)b * M_ * P_);
    const int4*   hb = (const int4*)(heart + (size_t)b * P_);
    const int vbase = chunk * (CHUNK / 4);

    float part = 0.f;
    #pragma unroll
    for (int it = 0; it < VPT; ++it) {
        const int v = vbase + it * THREADS + tid;
        const int4 h4 = hb[v];
        float4 pk[K_];
        float4 xm[M_];
        #pragma unroll
        for (int k = 0; k < K_; ++k) pk[k] = pb[k * (P_ / 4) + v];
        #pragma unroll
        for (int m = 0; m < M_; ++m) xm[m] = ib[m * (P_ / 4) + v];

        #define PIX3(C) do {                                                  \
            const float w = (h4.C == 1) ? 1.f : 0.f;                          \
            float mix = EPS;                                                  \
            _Pragma("unroll")                                                 \
            for (int k = 0; k < K_; ++k) {                                    \
                float e = 0.f;                                                \
                _Pragma("unroll")                                             \
                for (int m = 0; m < M_; ++m) {                                \
                    const float d = xm[m].C - mu[k][m];                       \
                    e = fmaf(-(d * d), iv[k][m], e);                          \
                }                                                             \
                mix = fmaf(pk[k].C * ck[k], __expf(e), mix);                  \
            }                                                                 \
            part = fmaf(w, __logf(mix), part);                                \
        } while (0)
        PIX3(x); PIX3(y); PIX3(z); PIX3(w);
        #undef PIX3
    }

    __shared__ float lds[4];
    const int lane = tid & 63, wid = tid >> 6;
    float v = part;
    #pragma unroll
    for (int off = 32; off; off >>= 1) v += __shfl_down(v, off);
    if (lane == 0) lds[wid] = v;
    __syncthreads();
    if (tid == 0) {
        const float s = lds[0] + lds[1] + lds[2] + lds[3];
        atomicAdd(out, -s * invn);
    }
}

extern "C" void kernel_launch(void* const* d_in, const int* in_sizes, int n_in,
                              void* d_out, int out_size, void* d_ws, size_t ws_size,
                              hipStream_t stream)
{
    const float* pred  = (const float*)d_in[0];
    const float* inp   = (const float*)d_in[1];
    const int*   heart = (const int*)d_in[2];
    float* out = (float*)d_out;
    float* ws  = (float*)d_ws;

    float* sums = ws;                 // B*29 floats
    float* der  = ws + B_ * NACC;     // B*29 floats

    hipMemsetAsync(sums, 0, B_ * NACC * sizeof(float), stream);
    hipMemsetAsync(out,  0, sizeof(float), stream);

    gmm_pass1<<<B_ * BLOCKS_PER_B, THREADS, 0, stream>>>(pred, inp, heart, sums);
    gmm_pass2<<<1, 256, 0, stream>>>(sums, der);
    gmm_pass3<<<B_ * BLOCKS_PER_B, THREADS, 0, stream>>>(pred, inp, heart, der, out);
}

// Round 4
// 69.114 us; speedup vs baseline: 1.0943x; 1.0943x over previous
//
#include <hip/hip_runtime.h>

#define EPS 1e-10f

constexpr int B_ = 64, K_ = 4, M_ = 3, P_ = 65536;
constexpr int THREADS = 256;
constexpr int CHUNK = 2048;                    // pixels per block
constexpr int BLOCKS_PER_B = P_ / CHUNK;       // 32  -> grid = 2048 blocks
constexpr int VPT = CHUNK / 4 / THREADS;       // (pass3) float4 iters per thread
constexpr int WAVE_ITERS = CHUNK / 4 / 64;     // 8 float4 iters per wave (pass1)
constexpr int NACC = 29;                       // 4 s + 12 t + 12 u + 1 n

// ---------------- pass 1: per-(b,k) weighted sums -------------------------
// Wave-per-k split: wave w owns mixture component k=w. Per-thread state is
// only 8 accumulators, so a 2-deep rolling prefetch (10 loads in flight)
// fits easily in registers. inp/heart are read by all 4 waves at the same
// addresses -> L1 hits, no extra HBM traffic.
__global__ __launch_bounds__(THREADS, 4) void gmm_pass1(
    const float* __restrict__ pred, const float* __restrict__ inp,
    const int* __restrict__ heart, float* __restrict__ sums)
{
    const int blk   = blockIdx.x;
    const int b     = blk / BLOCKS_PER_B;
    const int chunk = blk % BLOCKS_PER_B;
    const int tid   = threadIdx.x;
    const int wv    = tid >> 6;        // wave id = k
    const int lane  = tid & 63;

    const float4* pkb = (const float4*)(pred + ((size_t)b * K_ + wv) * P_);
    const float4* ib  = (const float4*)(inp  + (size_t)b * M_ * P_);
    const int4*   hb  = (const int4*)(heart + (size_t)b * P_);
    const int vbase = chunk * (CHUNK / 4);

    float s = 0.f, n = 0.f;
    float t0 = 0.f, t1 = 0.f, t2 = 0.f;
    float u0 = 0.f, u1 = 0.f, u2 = 0.f;

    // rolling 2-deep pipeline: loads for it+1 issued before compute of it
    int v = vbase + lane;
    float4 p_c  = pkb[v];
    float4 x0_c = ib[0 * (P_ / 4) + v];
    float4 x1_c = ib[1 * (P_ / 4) + v];
    float4 x2_c = ib[2 * (P_ / 4) + v];
    int4   h_c  = hb[v];

    #pragma unroll
    for (int it = 0; it < WAVE_ITERS; ++it) {
        float4 p_n, x0_n, x1_n, x2_n; int4 h_n;
        if (it + 1 < WAVE_ITERS) {
            const int vn = vbase + (it + 1) * 64 + lane;
            p_n  = pkb[vn];
            x0_n = ib[0 * (P_ / 4) + vn];
            x1_n = ib[1 * (P_ / 4) + vn];
            x2_n = ib[2 * (P_ / 4) + vn];
            h_n  = hb[vn];
        }

        #define PIX1(C) do {                                                  \
            const float w  = (h_c.C == 1) ? 1.f : 0.f;                        \
            const float pw = p_c.C * w;                                       \
            n += w; s += pw;                                                  \
            t0 = fmaf(pw, x0_c.C, t0);                                        \
            u0 = fmaf(pw * x0_c.C, x0_c.C, u0);                               \
            t1 = fmaf(pw, x1_c.C, t1);                                        \
            u1 = fmaf(pw * x1_c.C, x1_c.C, u1);                               \
            t2 = fmaf(pw, x2_c.C, t2);                                        \
            u2 = fmaf(pw * x2_c.C, x2_c.C, u2);                               \
        } while (0)
        PIX1(x); PIX1(y); PIX1(z); PIX1(w);
        #undef PIX1

        if (it + 1 < WAVE_ITERS) {
            p_c = p_n; x0_c = x0_n; x1_c = x1_n; x2_c = x2_n; h_c = h_n;
        }
    }

    // wave-internal reduction of the 8 values (independent shfl chains)
    float vals[8] = { s, t0, t1, t2, u0, u1, u2, n };
    __shared__ float lds[4 * 8];
    #pragma unroll
    for (int j = 0; j < 8; ++j) {
        float x = vals[j];
        #pragma unroll
        for (int off = 32; off; off >>= 1) x += __shfl_down(x, off);
        vals[j] = x;
    }
    if (lane == 0) {
        #pragma unroll
        for (int j = 0; j < 8; ++j) lds[wv * 8 + j] = vals[j];
    }
    __syncthreads();
    if (tid < 32) {
        const int w = tid >> 3, j = tid & 7;
        int idx;
        bool emit = true;
        if (j == 0)      idx = w;                 // s_k
        else if (j <= 3) idx = 4  + w * 3 + (j - 1);  // t_km
        else if (j <= 6) idx = 16 + w * 3 + (j - 4);  // u_km
        else { idx = 28; emit = (w == 0); }       // n (once)
        if (emit) atomicAdd(&sums[b * NACC + idx], lds[tid]);
    }
}

// ---------------- pass 2: derive mu, 1/(2var), coef, 1/(n*B) --------------
__global__ void gmm_pass2(const float* __restrict__ sums, float* __restrict__ der)
{
    const int t = blockIdx.x * blockDim.x + threadIdx.x;   // = b*K + k
    if (t >= B_ * K_) return;
    const int b = t / K_, k = t % K_;
    const float* sb = sums + b * NACC;
    float* db = der + b * NACC;   // layout: mu[12], iv[12], c[4], invn[1]

    const float s = sb[k] + EPS;
    const float inv_s = 1.f / s;
    float c = 1.f;
    #pragma unroll
    for (int m = 0; m < M_; ++m) {
        const float tkm = sb[4  + k * M_ + m];
        const float ukm = sb[16 + k * M_ + m];
        const float mu  = tkm * inv_s;
        const float var = fmaf(-mu, mu, ukm * inv_s) + EPS;
        db[k * M_ + m]      = mu;
        db[12 + k * M_ + m] = 0.5f / var;
        c *= rsqrtf(6.283185307179586f * var);
    }
    db[24 + k] = c;
    if (k == 0) db[28] = 1.f / (sb[28] * (float)B_);
}

// ---------------- pass 3: mixture log-likelihood, masked mean -------------
__global__ __launch_bounds__(THREADS, 4) void gmm_pass3(
    const float* __restrict__ pred, const float* __restrict__ inp,
    const int* __restrict__ heart, const float* __restrict__ der,
    float* __restrict__ out)
{
    const int blk   = blockIdx.x;
    const int b     = blk / BLOCKS_PER_B;
    const int chunk = blk % BLOCKS_PER_B;
    const int tid   = threadIdx.x;

    const float* db = der + b * NACC;
    float mu[K_][M_], iv[K_][M_], ck[K_];
    #pragma unroll
    for (int k = 0; k < K_; ++k) {
        #pragma unroll
        for (int m = 0; m < M_; ++m) {
            mu[k][m] = db[k * M_ + m];
            iv[k][m] = db[12 + k * M_ + m];
        }
        ck[k] = db[24 + k];
    }
    const float invn = db[28];

    const float4* pb = (const float4*)(pred + (size_t)b * K_ * P_);
    const float4* ib = (const float4*)(inp  + (size_t)b * M_ * P_);
    const int4*   hb = (const int4*)(heart + (size_t)b * P_);
    const int vbase = chunk * (CHUNK / 4);

    float part = 0.f;
    #pragma unroll
    for (int it = 0; it < VPT; ++it) {
        const int v = vbase + it * THREADS + tid;
        const int4 h4 = hb[v];
        float4 pk[K_];
        float4 xm[M_];
        #pragma unroll
        for (int k = 0; k < K_; ++k) pk[k] = pb[k * (P_ / 4) + v];
        #pragma unroll
        for (int m = 0; m < M_; ++m) xm[m] = ib[m * (P_ / 4) + v];

        #define PIX3(C) do {                                                  \
            const float w = (h4.C == 1) ? 1.f : 0.f;                          \
            float mix = EPS;                                                  \
            _Pragma("unroll")                                                 \
            for (int k = 0; k < K_; ++k) {                                    \
                float e = 0.f;                                                \
                _Pragma("unroll")                                             \
                for (int m = 0; m < M_; ++m) {                                \
                    const float d = xm[m].C - mu[k][m];                       \
                    e = fmaf(-(d * d), iv[k][m], e);                          \
                }                                                             \
                mix = fmaf(pk[k].C * ck[k], __expf(e), mix);                  \
            }                                                                 \
            part = fmaf(w, __logf(mix), part);                                \
        } while (0)
        PIX3(x); PIX3(y); PIX3(z); PIX3(w);
        #undef PIX3
    }

    __shared__ float lds[4];
    const int lane = tid & 63, wid = tid >> 6;
    float v = part;
    #pragma unroll
    for (int off = 32; off; off >>= 1) v += __shfl_down(v, off);
    if (lane == 0) lds[wid] = v;
    __syncthreads();
    if (tid == 0) {
        const float s = lds[0] + lds[1] + lds[2] + lds[3];
        atomicAdd(out, -s * invn);
    }
}

extern "C" void kernel_launch(void* const* d_in, const int* in_sizes, int n_in,
                              void* d_out, int out_size, void* d_ws, size_t ws_size,
                              hipStream_t stream)
{
    const float* pred  = (const float*)d_in[0];
    const float* inp   = (const float*)d_in[1];
    const int*   heart = (const int*)d_in[2];
    float* out = (float*)d_out;
    float* ws  = (float*)d_ws;

    float* sums = ws;                 // B*29 floats
    float* der  = ws + B_ * NACC;     // B*29 floats

    hipMemsetAsync(sums, 0, B_ * NACC * sizeof(float), stream);
    hipMemsetAsync(out,  0, sizeof(float), stream);

    gmm_pass1<<<B_ * BLOCKS_PER_B, THREADS, 0, stream>>>(pred, inp, heart, sums);
    gmm_pass2<<<1, 256, 0, stream>>>(sums, der);
    gmm_pass3<<<B_ * BLOCKS_PER_B, THREADS, 0, stream>>>(pred, inp, heart, der, out);
}

// Round 5
// 67.132 us; speedup vs baseline: 1.1266x; 1.0295x over previous
//
#include <hip/hip_runtime.h>

#define EPS 1e-10f

constexpr int B_ = 64, K_ = 4, M_ = 3, P_ = 65536;
constexpr int THREADS = 256;
constexpr int CHUNK = 4096;                    // pixels per block
constexpr int BLOCKS_PER_B = P_ / CHUNK;       // 16 -> grid = 1024 blocks
constexpr int TILE = 512;                      // pixels per LDS tile
constexpr int NT = CHUNK / TILE;               // 8 tiles per block
constexpr int NPL = 8;                         // planes: pred k0..3, inp m0..2, heart
constexpr int NACC = 29;                       // 4 s + 12 t + 12 u + 1 n

// Stage one 512-px tile (8 planes, 16 KB) into LDS via global_load_lds.
// 16 rows of 1 KB; wave w stages rows w*4 .. w*4+3. LDS dest is wave-uniform
// base + lane*16 (m104 semantics); global src is per-lane rowbase + lane*4.
__device__ __forceinline__ void stage_tile(
    const float* __restrict__ pred, const float* __restrict__ inp,
    const int* __restrict__ heart, int b, int pix0,
    float (*sbuf)[NPL][TILE], int buf, int wv, int lane)
{
    #pragma unroll
    for (int j = 0; j < 4; ++j) {
        const int r  = wv * 4 + j;
        const int pl = r >> 1;
        const int hf = r & 1;
        const float* g;
        if (pl < 4)       g = pred + ((size_t)(b * K_ + pl)) * P_ + pix0 + hf * 256;
        else if (pl < 7)  g = inp  + ((size_t)(b * M_ + (pl - 4))) * P_ + pix0 + hf * 256;
        else              g = (const float*)(heart + (size_t)b * P_ + pix0 + hf * 256);
        __builtin_amdgcn_global_load_lds(g + lane * 4, &sbuf[buf][pl][hf * 256], 16, 0, 0);
    }
}

// ---------------- pass 1: per-(b,k) weighted sums -------------------------
__global__ __launch_bounds__(THREADS, 4) void gmm_pass1(
    const float* __restrict__ pred, const float* __restrict__ inp,
    const int* __restrict__ heart, float* __restrict__ sums)
{
    __shared__ float sbuf[2][NPL][TILE];
    const int blk   = blockIdx.x;
    const int b     = blk / BLOCKS_PER_B;
    const int chunk = blk % BLOCKS_PER_B;
    const int tid   = threadIdx.x;
    const int wv    = tid >> 6;        // wave id = mixture component k
    const int lane  = tid & 63;
    const int base  = chunk * CHUNK;

    float s = 0.f, n = 0.f;
    float t0 = 0.f, t1 = 0.f, t2 = 0.f;
    float u0 = 0.f, u1 = 0.f, u2 = 0.f;

    // prologue: stage tile 0
    stage_tile(pred, inp, heart, b, base, sbuf, 0, wv, lane);
    __syncthreads();

    for (int t = 0; t < NT; ++t) {
        const int cur = t & 1;
        if (t + 1 < NT)
            stage_tile(pred, inp, heart, b, base + (t + 1) * TILE, sbuf, cur ^ 1, wv, lane);
        __builtin_amdgcn_sched_barrier(0);   // keep stage-issue above the ds_reads

        const float* pk  = &sbuf[cur][wv][0];
        const float* x0p = &sbuf[cur][4][0];
        const float* x1p = &sbuf[cur][5][0];
        const float* x2p = &sbuf[cur][6][0];
        const int*   hp  = (const int*)&sbuf[cur][7][0];

        #pragma unroll
        for (int g = 0; g < TILE / 64; ++g) {
            const int px = g * 64 + lane;
            const float w  = (hp[px] == 1) ? 1.f : 0.f;
            const float pw = pk[px] * w;
            n += w; s += pw;
            float x;
            x = x0p[px]; t0 = fmaf(pw, x, t0); u0 = fmaf(pw * x, x, u0);
            x = x1p[px]; t1 = fmaf(pw, x, t1); u1 = fmaf(pw * x, x, u1);
            x = x2p[px]; t2 = fmaf(pw, x, t2); u2 = fmaf(pw * x, x, u2);
        }
        __syncthreads();   // drains next tile's global_load_lds + buffer handoff
    }

    // wave-internal reduction of the 8 values
    float vals[8] = { s, t0, t1, t2, u0, u1, u2, n };
    __shared__ float lds[4 * 8];
    #pragma unroll
    for (int j = 0; j < 8; ++j) {
        float x = vals[j];
        #pragma unroll
        for (int off = 32; off; off >>= 1) x += __shfl_down(x, off);
        vals[j] = x;
    }
    if (lane == 0) {
        #pragma unroll
        for (int j = 0; j < 8; ++j) lds[wv * 8 + j] = vals[j];
    }
    __syncthreads();
    if (tid < 32) {
        const int w = tid >> 3, j = tid & 7;
        int idx;
        bool emit = true;
        if (j == 0)      idx = w;                     // s_k
        else if (j <= 3) idx = 4  + w * 3 + (j - 1);  // t_km
        else if (j <= 6) idx = 16 + w * 3 + (j - 4);  // u_km
        else { idx = 28; emit = (w == 0); }           // n (once)
        if (emit) atomicAdd(&sums[b * NACC + idx], lds[tid]);
    }
}

// ---------------- pass 2: derive mu, 1/(2var), coef, 1/(n*B) --------------
__global__ void gmm_pass2(const float* __restrict__ sums, float* __restrict__ der)
{
    const int t = blockIdx.x * blockDim.x + threadIdx.x;   // = b*K + k
    if (t >= B_ * K_) return;
    const int b = t / K_, k = t % K_;
    const float* sb = sums + b * NACC;
    float* db = der + b * NACC;   // layout: mu[12], iv[12], c[4], invn[1]

    const float s = sb[k] + EPS;
    const float inv_s = 1.f / s;
    float c = 1.f;
    #pragma unroll
    for (int m = 0; m < M_; ++m) {
        const float tkm = sb[4  + k * M_ + m];
        const float ukm = sb[16 + k * M_ + m];
        const float mu  = tkm * inv_s;
        const float var = fmaf(-mu, mu, ukm * inv_s) + EPS;
        db[k * M_ + m]      = mu;
        db[12 + k * M_ + m] = 0.5f / var;
        c *= rsqrtf(6.283185307179586f * var);
    }
    db[24 + k] = c;
    if (k == 0) db[28] = 1.f / (sb[28] * (float)B_);
}

// ---------------- pass 3: mixture log-likelihood, masked mean -------------
__global__ __launch_bounds__(THREADS, 3) void gmm_pass3(
    const float* __restrict__ pred, const float* __restrict__ inp,
    const int* __restrict__ heart, const float* __restrict__ der,
    float* __restrict__ out)
{
    __shared__ float sbuf[2][NPL][TILE];
    const int blk   = blockIdx.x;
    const int b     = blk / BLOCKS_PER_B;
    const int chunk = blk % BLOCKS_PER_B;
    const int tid   = threadIdx.x;
    const int wv    = tid >> 6;
    const int lane  = tid & 63;
    const int base  = chunk * CHUNK;

    const float* db = der + b * NACC;
    float mu[K_][M_], iv[K_][M_], ck[K_];
    #pragma unroll
    for (int k = 0; k < K_; ++k) {
        #pragma unroll
        for (int m = 0; m < M_; ++m) {
            mu[k][m] = db[k * M_ + m];
            iv[k][m] = db[12 + k * M_ + m];
        }
        ck[k] = db[24 + k];
    }
    const float invn = db[28];

    float part = 0.f;

    stage_tile(pred, inp, heart, b, base, sbuf, 0, wv, lane);
    __syncthreads();

    for (int t = 0; t < NT; ++t) {
        const int cur = t & 1;
        if (t + 1 < NT)
            stage_tile(pred, inp, heart, b, base + (t + 1) * TILE, sbuf, cur ^ 1, wv, lane);
        __builtin_amdgcn_sched_barrier(0);

        const int* hp = (const int*)&sbuf[cur][7][0];
        #pragma unroll
        for (int i = 0; i < TILE / THREADS; ++i) {
            const int px = i * THREADS + tid;
            const float w = (hp[px] == 1) ? 1.f : 0.f;
            const float x0 = sbuf[cur][4][px];
            const float x1 = sbuf[cur][5][px];
            const float x2 = sbuf[cur][6][px];
            float mix = EPS;
            #pragma unroll
            for (int k = 0; k < K_; ++k) {
                const float d0 = x0 - mu[k][0];
                const float d1 = x1 - mu[k][1];
                const float d2 = x2 - mu[k][2];
                float e = -(d0 * d0) * iv[k][0];
                e = fmaf(-(d1 * d1), iv[k][1], e);
                e = fmaf(-(d2 * d2), iv[k][2], e);
                mix = fmaf(sbuf[cur][k][px] * ck[k], __expf(e), mix);
            }
            part = fmaf(w, __logf(mix), part);
        }
        __syncthreads();
    }

    __shared__ float lds[4];
    float v = part;
    #pragma unroll
    for (int off = 32; off; off >>= 1) v += __shfl_down(v, off);
    if (lane == 0) lds[wv] = v;
    __syncthreads();
    if (tid == 0) {
        const float ssum = lds[0] + lds[1] + lds[2] + lds[3];
        atomicAdd(out, -ssum * invn);
    }
}

extern "C" void kernel_launch(void* const* d_in, const int* in_sizes, int n_in,
                              void* d_out, int out_size, void* d_ws, size_t ws_size,
                              hipStream_t stream)
{
    const float* pred  = (const float*)d_in[0];
    const float* inp   = (const float*)d_in[1];
    const int*   heart = (const int*)d_in[2];
    float* out = (float*)d_out;
    float* ws  = (float*)d_ws;

    float* sums = ws;                 // B*29 floats
    float* der  = ws + B_ * NACC;     // B*29 floats

    hipMemsetAsync(sums, 0, B_ * NACC * sizeof(float), stream);
    hipMemsetAsync(out,  0, sizeof(float), stream);

    gmm_pass1<<<B_ * BLOCKS_PER_B, THREADS, 0, stream>>>(pred, inp, heart, sums);
    gmm_pass2<<<1, 256, 0, stream>>>(sums, der);
    gmm_pass3<<<B_ * BLOCKS_PER_B, THREADS, 0, stream>>>(pred, inp, heart, der, out);
}